// Round 1
// baseline (808.309 us; speedup 1.0000x reference)
//
#include <hip/hip_runtime.h>
#include <hip/hip_bf16.h>
#include <stdint.h>
#include <stddef.h>

typedef short v8s __attribute__((ext_vector_type(8)));
typedef float v4f __attribute__((ext_vector_type(4)));

#define NBATCH 64
#define MDIM   256
#define NDIM   512
#define NBL    8
#define ROWS   (NBATCH * NBL)   /* 512 GEMM rows (b*8+i) */
#define KF     NDIM             /* 512: GEMM1 K */
#define NGF    (MDIM * NBL)     /* 2048: GEMM1 N */
#define KB     MDIM             /* 256: GEMM2 K */
#define NGB    (NDIM * NBL)     /* 4096: GEMM2 N */
#define STEPSZ 0.01f

/* workspace layout (bytes) */
#define OFF_ARE 0u                      /* bf16 [2048][512]: 2 MB  (B^T for GEMM1) */
#define OFF_ATT (2u << 20)              /* bf16 [4096][256]: 2 MB  (B^T for GEMM2) */
#define OFF_XF  (4u << 20)              /* f32  [512][512] : 1 MB  (x master)      */
#define OFF_XB  (5u << 20)              /* bf16 [512][512] : 0.5MB (x operand)     */
#define OFF_ERR (OFF_XB + ROWS * NDIM * 2u) /* bf16 [512][256]: 0.25MB (err operand) */

__device__ __forceinline__ void async_lds16(const void* g, void* l) {
  __builtin_amdgcn_global_load_lds(
      (const __attribute__((address_space(1))) uint32_t*)g,
      (__attribute__((address_space(3))) uint32_t*)l, 16, 0, 0);
}

/* A_reT[(m*8+j)*512 + n] = A[m,n,j]  (bf16) */
__global__ void prep_fwd(const float* __restrict__ A, __hip_bfloat16* __restrict__ AreT) {
  const int m = blockIdx.x;   // 256
  const int n = threadIdx.x;  // 512
  const float* ap = A + ((size_t)m * NDIM + n) * NBL;
#pragma unroll
  for (int j = 0; j < NBL; ++j)
    AreT[((size_t)(m * NBL + j)) * NDIM + n] = __float2bfloat16(ap[j]);
}

/* At_reT[(n*8+j)*256 + m] = A[m,n,j] * rev[j]  (bf16) */
__global__ void prep_bwd(const float* __restrict__ A, __hip_bfloat16* __restrict__ AtT) {
  const int n = blockIdx.x;   // 512
  const int m = threadIdx.x;  // 256
  const float* ap = A + ((size_t)m * NDIM + n) * NBL;
  const float rev[8] = {1.f, 1.f, 1.f, -1.f, 1.f, -1.f, -1.f, -1.f};
#pragma unroll
  for (int j = 0; j < NBL; ++j)
    AtT[((size_t)(n * NBL + j)) * MDIM + m] = __float2bfloat16(ap[j] * rev[j]);
}

__global__ void zero_x(float* __restrict__ xf, __hip_bfloat16* __restrict__ xb) {
  const int idx = blockIdx.x * blockDim.x + threadIdx.x;  // 262144
  xf[idx] = 0.f;
  xb[idx] = __float2bfloat16(0.f);
}

/* out[b,n,k] = x[(b*8+k), n] */
__global__ void finalize(const float* __restrict__ xf, float* __restrict__ out) {
  const int idx = blockIdx.x * blockDim.x + threadIdx.x;  // 262144
  const int k = idx & 7;
  const int n = (idx >> 3) & (NDIM - 1);
  const int b = idx >> 12;
  out[idx] = xf[((size_t)(b * NBL + k) << 9) | n];
}

/* One GEMM step, 64x64 tile, 4 waves of 2x2 16x16x32 bf16 MFMA.
 * PHASE 1: P = x_bf @ AreT^T; epilogue: blade-recombine, subtract y -> err_bf16
 * PHASE 2: Q = err_bf @ AtT^T; epilogue: blade-recombine -> grad; x update + soft-threshold
 */
template <int PHASE>
__global__ __launch_bounds__(256) void gemm_step(
    const __hip_bfloat16* __restrict__ Aop, const __hip_bfloat16* __restrict__ Bt,
    const float* __restrict__ y, __hip_bfloat16* __restrict__ errb,
    float* __restrict__ xf, __hip_bfloat16* __restrict__ xb) {
  constexpr int K = (PHASE == 1) ? KF : KB;

  __shared__ __align__(16) __hip_bfloat16 As[64 * 32];
  __shared__ __align__(16) __hip_bfloat16 Bs[64 * 32];
  __shared__ float Pt[64 * 68];

  const int tid = threadIdx.x;
  const int wave = tid >> 6;
  const int lane = tid & 63;
  const int r0 = blockIdx.y * 64;  // row tile: (b,i) rows
  const int c0 = blockIdx.x * 64;  // col tile: (m,j) / (n,j) cols

  const int wr = (wave >> 1) * 32;  // wave row offset within tile
  const int wc = (wave & 1) * 32;   // wave col offset within tile

  v4f acc[2][2] = {};

  // staging addresses: thread t loads 16B: row = t/4, k-chunk = (t%4)*8
  const int srow = tid >> 2;
  const int schunk = (tid & 3) * 8;
  const __hip_bfloat16* gA = Aop + (size_t)(r0 + srow) * K + schunk;
  const __hip_bfloat16* gB = Bt + (size_t)(c0 + srow) * K + schunk;
  __hip_bfloat16* lA = As + wave * 512;  // wave-uniform LDS base (+lane*16B by HW)
  __hip_bfloat16* lB = Bs + wave * 512;

  for (int k0 = 0; k0 < K; k0 += 32) {
    async_lds16(gA + k0, lA);
    async_lds16(gB + k0, lB);
    __syncthreads();

    const int fr = lane & 15;
    const int fq = (lane >> 4) * 8;
    v8s a0 = *(const v8s*)&As[(wr + fr) * 32 + fq];
    v8s a1 = *(const v8s*)&As[(wr + 16 + fr) * 32 + fq];
    v8s b0 = *(const v8s*)&Bs[(wc + fr) * 32 + fq];
    v8s b1 = *(const v8s*)&Bs[(wc + 16 + fr) * 32 + fq];
    acc[0][0] = __builtin_amdgcn_mfma_f32_16x16x32_bf16(a0, b0, acc[0][0], 0, 0, 0);
    acc[0][1] = __builtin_amdgcn_mfma_f32_16x16x32_bf16(a0, b1, acc[0][1], 0, 0, 0);
    acc[1][0] = __builtin_amdgcn_mfma_f32_16x16x32_bf16(a1, b0, acc[1][0], 0, 0, 0);
    acc[1][1] = __builtin_amdgcn_mfma_f32_16x16x32_bf16(a1, b1, acc[1][1], 0, 0, 0);
    __syncthreads();
  }

  // dump accumulators to LDS for the cross-lane 8x8 blade recombine
  const int pr = (lane >> 4) * 4;
  const int pc = lane & 15;
#pragma unroll
  for (int r = 0; r < 2; ++r)
#pragma unroll
    for (int c = 0; c < 2; ++c)
#pragma unroll
      for (int v = 0; v < 4; ++v)
        Pt[(wr + r * 16 + pr + v) * 68 + wc + c * 16 + pc] = acc[r][c][v];
  __syncthreads();

  // 512 outputs per tile: (b_local, k, m_local); out[k] = sum_j s(k^j,j)*P[i=k^j][j]
  for (int o = tid; o < 512; o += 256) {
    const int bl = o >> 6;
    const int k = (o >> 3) & 7;
    const int ml = o & 7;
    float s = 0.f;
#pragma unroll
    for (int j = 0; j < 8; ++j) {
      const int i = k ^ j;
      const int cnt = __popc((i >> 1) & j) + __popc((i >> 2) & j);  // reorder parity
      const float p = Pt[(bl * 8 + i) * 68 + ml * 8 + j];
      s += (cnt & 1) ? -p : p;
    }
    const int b = blockIdx.y * 8 + bl;
    if (PHASE == 1) {
      const int m = blockIdx.x * 8 + ml;
      const float e = s - y[((size_t)b * MDIM + m) * NBL + k];
      errb[(size_t)(b * NBL + k) * MDIM + m] = __float2bfloat16(e);
    } else {
      const int n = blockIdx.x * 8 + ml;
      const size_t idx = (size_t)(b * NBL + k) * NDIM + n;
      float xv = xf[idx] - STEPSZ * s;
      const float thr = (k == 0) ? 0.f : ((k == 7) ? 0.002f : 0.001f);
      const float ax = fabsf(xv) - thr;
      xv = (ax > 0.f) ? copysignf(ax, xv) : 0.f;
      xf[idx] = xv;
      xb[idx] = __float2bfloat16(xv);
    }
  }
}

extern "C" void kernel_launch(void* const* d_in, const int* in_sizes, int n_in,
                              void* d_out, int out_size, void* d_ws, size_t ws_size,
                              hipStream_t stream) {
  (void)in_sizes; (void)n_in; (void)out_size; (void)ws_size;
  const float* y = (const float*)d_in[0];
  const float* A = (const float*)d_in[1];
  float* out = (float*)d_out;
  char* ws = (char*)d_ws;

  __hip_bfloat16* AreT = (__hip_bfloat16*)(ws + OFF_ARE);
  __hip_bfloat16* AtT = (__hip_bfloat16*)(ws + OFF_ATT);
  float* xf = (float*)(ws + OFF_XF);
  __hip_bfloat16* xb = (__hip_bfloat16*)(ws + OFF_XB);
  __hip_bfloat16* errb = (__hip_bfloat16*)(ws + OFF_ERR);

  prep_fwd<<<MDIM, NDIM, 0, stream>>>(A, AreT);
  prep_bwd<<<NDIM, MDIM, 0, stream>>>(A, AtT);
  zero_x<<<1024, 256, 0, stream>>>(xf, xb);

  for (int it = 0; it < 50; ++it) {
    gemm_step<1><<<dim3(NGF / 64, ROWS / 64), 256, 0, stream>>>(xb, AreT, y, errb, xf, xb);
    gemm_step<2><<<dim3(NGB / 64, ROWS / 64), 256, 0, stream>>>(errb, AtT, y, errb, xf, xb);
  }

  finalize<<<1024, 256, 0, stream>>>(xf, out);
}